// Round 3
// baseline (2356.383 us; speedup 1.0000x reference)
//
#include <hip/hip_runtime.h>
#include <hip/hip_bf16.h>

#define L_TOK 3072
#define HIDN  2048
#define NHQ   16
#define NHKV  4
#define DH    128
#define DFFN  8192
#define NTXT  256

typedef float f32x4 __attribute__((ext_vector_type(4)));
typedef short s16x8 __attribute__((ext_vector_type(8)));
typedef unsigned int u32;
typedef unsigned short u16;

__device__ __forceinline__ u16 f2bf(float f) {
    union { float f; u32 u; } v; v.f = f;
    u32 r = v.u + 0x7fffu + ((v.u >> 16) & 1u);
    return (u16)(r >> 16);
}
__device__ __forceinline__ float bf2f(u16 b) {
    union { u32 u; float f; } v; v.u = ((u32)b) << 16;
    return v.f;
}
__device__ __forceinline__ u32 pack2(float lo, float hi) {
    return (u32)f2bf(lo) | ((u32)f2bf(hi) << 16);
}

#define MFMA16(a, b, c) __builtin_amdgcn_mfma_f32_16x16x32_bf16((a), (b), (c), 0, 0, 0)

// ---------------------------------------------------------------------------
// RMSNorm: f32 in -> bf16 out, weight selected by row<NTXT (text) else vae.
// ---------------------------------------------------------------------------
__global__ __launch_bounds__(256) void rms_kernel(
    const float* __restrict__ x, const float* __restrict__ w_t,
    const float* __restrict__ w_v, u16* __restrict__ out)
{
    int row = blockIdx.x;
    const float* w = (row < NTXT) ? w_t : w_v;
    const float* xr = x + (size_t)row * HIDN;
    int t = threadIdx.x;
    f32x4 a = *(const f32x4*)(xr + t * 8);
    f32x4 b = *(const f32x4*)(xr + t * 8 + 4);
    float s = 0.f;
#pragma unroll
    for (int i = 0; i < 4; i++) s += a[i] * a[i] + b[i] * b[i];
#pragma unroll
    for (int m = 32; m >= 1; m >>= 1) s += __shfl_xor(s, m);
    __shared__ float red[4];
    if ((t & 63) == 0) red[t >> 6] = s;
    __syncthreads();
    s = red[0] + red[1] + red[2] + red[3];
    float scale = rsqrtf(s * (1.0f / HIDN) + 1e-6f);
    f32x4 wa = *(const f32x4*)(w + t * 8);
    f32x4 wb = *(const f32x4*)(w + t * 8 + 4);
    u32 o[4];
    o[0] = pack2(a[0] * wa[0] * scale, a[1] * wa[1] * scale);
    o[1] = pack2(a[2] * wa[2] * scale, a[3] * wa[3] * scale);
    o[2] = pack2(b[0] * wb[0] * scale, b[1] * wb[1] * scale);
    o[3] = pack2(b[2] * wb[2] * scale, b[3] * wb[3] * scale);
    *(uint4*)(out + (size_t)row * HIDN + t * 8) = make_uint4(o[0], o[1], o[2], o[3]);
}

// ---------------------------------------------------------------------------
// GEMM: C[M,N] = A[M,K](bf16) * B[K,N](f32, cast to bf16 on the fly)
// 128x128 tile, 4 waves, mfma 16x16x32 bf16.
// EPI: 0 = store f32, 1 = store f32 + residual, 2 = store bf16
// ---------------------------------------------------------------------------
template<int EPI>
__global__ __launch_bounds__(256) void gemm_kernel(
    const u16* __restrict__ A, int lda,
    const float* __restrict__ B, int ldb,
    void* __restrict__ Cv, int ldc,
    const float* __restrict__ R, int ldr,
    int K)
{
    __shared__ __align__(16) u16 As[128 * 40];   // [row][k] stride 40 shorts (80B)
    __shared__ __align__(16) u32 Bs[128 * 20];   // [n][kpair] stride 20 u32 (80B), group-XOR swizzled

    int tid = threadIdx.x;
    int l = tid & 63, w = tid >> 6;
    int wr = w >> 1, wc = w & 1;
    int lg = l >> 4, lr = l & 15;
    int brow = blockIdx.y * 128, bcol = blockIdx.x * 128;
    A += (size_t)brow * lda;
    B += bcol;

    f32x4 acc[4][4];
    f32x4 z4 = {0.f, 0.f, 0.f, 0.f};
#pragma unroll
    for (int m = 0; m < 4; m++)
#pragma unroll
        for (int n = 0; n < 4; n++) acc[m][n] = z4;

    // staging indices
    int arow = tid >> 1, acol = (tid & 1) * 16;
    const u16* aptr = A + (size_t)arow * lda + acol;
    int kp = tid >> 4, n8 = (tid & 15) * 8;
    const float* bptr = B + (size_t)(2 * kp) * ldb + n8;
    int g4 = (((kp >> 2) ^ ((n8 >> 3) & 3)) << 2) + (kp & 3);

    for (int k0 = 0; k0 < K; k0 += 32) {
        f32x4 av0 = *(const f32x4*)(aptr);
        f32x4 av1 = *(const f32x4*)(aptr + 8);
        aptr += 32;
        f32x4 b00 = *(const f32x4*)(bptr);
        f32x4 b01 = *(const f32x4*)(bptr + 4);
        f32x4 b10 = *(const f32x4*)(bptr + ldb);
        f32x4 b11 = *(const f32x4*)(bptr + ldb + 4);
        bptr += (size_t)32 * ldb;

        *(f32x4*)&As[arow * 40 + acol] = av0;
        *(f32x4*)&As[arow * 40 + acol + 8] = av1;
#pragma unroll
        for (int j = 0; j < 4; j++) Bs[(n8 + j) * 20 + g4] = pack2(b00[j], b10[j]);
#pragma unroll
        for (int j = 0; j < 4; j++) Bs[(n8 + 4 + j) * 20 + g4] = pack2(b01[j], b11[j]);
        __syncthreads();

        s16x8 af[4], bf[4];
#pragma unroll
        for (int m = 0; m < 4; m++)
            af[m] = *(const s16x8*)&As[(wr * 64 + m * 16 + lr) * 40 + lg * 8];
#pragma unroll
        for (int n = 0; n < 4; n++) {
            int col = wc * 64 + n * 16 + lr;
            int gg = (lg ^ ((col >> 3) & 3)) << 2;
            bf[n] = *(const s16x8*)&Bs[col * 20 + gg];
        }
#pragma unroll
        for (int m = 0; m < 4; m++)
#pragma unroll
            for (int n = 0; n < 4; n++)
                acc[m][n] = MFMA16(af[m], bf[n], acc[m][n]);
        __syncthreads();
    }

#pragma unroll
    for (int m = 0; m < 4; m++) {
        int rowb = brow + wr * 64 + m * 16 + lg * 4;
#pragma unroll
        for (int n = 0; n < 4; n++) {
            int col = bcol + wc * 64 + n * 16 + lr;
#pragma unroll
            for (int r = 0; r < 4; r++) {
                float v = acc[m][n][r];
                size_t idx = (size_t)(rowb + r) * ldc + col;
                if (EPI == 0) {
                    ((float*)Cv)[idx] = v;
                } else if (EPI == 1) {
                    ((float*)Cv)[idx] = v + R[(size_t)(rowb + r) * ldr + col];
                } else {
                    ((u16*)Cv)[idx] = f2bf(v);
                }
            }
        }
    }
}

// ---------------------------------------------------------------------------
// Post-QKV: per (token, unit) with unit in [0,24): q-heads 0..15 (rms+rope),
// k-heads 16..19 (rms+rope), v-heads 20..23 (cast only). 64 threads.
// ---------------------------------------------------------------------------
__global__ __launch_bounds__(64) void qkv_post_kernel(
    const float* __restrict__ qkv,
    const float* __restrict__ cosb, const float* __restrict__ sinb,
    const float* __restrict__ qn_t, const float* __restrict__ qn_v,
    const float* __restrict__ kn_t, const float* __restrict__ kn_v,
    u16* __restrict__ qo, u16* __restrict__ ko, u16* __restrict__ vo)
{
    int tok = blockIdx.y;
    int unit = blockIdx.x;
    int lane = threadIdx.x;
    const float* base = qkv + (size_t)tok * 3072;

    if (unit < NHQ + NHKV) {
        int isq = (unit < NHQ);
        int h = isq ? unit : (unit - NHQ);
        const float* src = base + (isq ? h * DH : 2048 + h * DH);
        float x0 = src[lane], x1 = src[lane + 64];
        float ss = x0 * x0 + x1 * x1;
#pragma unroll
    for (int m = 32; m >= 1; m >>= 1) ss += __shfl_xor(ss, m);
        float sc = rsqrtf(ss * (1.0f / DH) + 1e-6f);
        const float* nw = isq ? (tok < NTXT ? qn_t : qn_v) : (tok < NTXT ? kn_t : kn_v);
        float n0 = x0 * nw[lane] * sc, n1 = x1 * nw[lane + 64] * sc;
        float c0 = cosb[(size_t)tok * DH + lane], c1 = cosb[(size_t)tok * DH + lane + 64];
        float s0 = sinb[(size_t)tok * DH + lane], s1 = sinb[(size_t)tok * DH + lane + 64];
        float r0 = n0 * c0 - n1 * s0;
        float r1 = n1 * c1 + n0 * s1;
        if (isq) {
            u16* dst = qo + (size_t)tok * 2048 + h * DH;
            dst[lane] = f2bf(r0); dst[lane + 64] = f2bf(r1);
        } else {
            u16* dst = ko + (size_t)tok * 512 + h * DH;
            dst[lane] = f2bf(r0); dst[lane + 64] = f2bf(r1);
        }
    } else {
        int h = unit - NHQ - NHKV;
        const float* src = base + 2560 + h * DH;
        u16* dst = vo + (size_t)tok * 512 + h * DH;
        dst[lane] = f2bf(src[lane]);
        dst[lane + 64] = f2bf(src[lane + 64]);
    }
}

// ---------------------------------------------------------------------------
// Flash attention, causal, GQA 16/4. 1 wave per block; block = (qtile of 16) x head.
// Swapped QK^T: ST = mfma(Kfrag, Qfrag) so both frags are contiguous 16B loads.
// ---------------------------------------------------------------------------
__global__ __launch_bounds__(64) void attn_kernel(
    const u16* __restrict__ Q, const u16* __restrict__ Kb,
    const u16* __restrict__ Vb, u16* __restrict__ O)
{
    __shared__ __align__(16) u16 Plds[16 * 40];   // [q][kv] stride 40
    __shared__ __align__(16) u32 Vt[128 * 20];    // [d][kvpair] stride 20 u32

    int l = threadIdx.x;
    int head = blockIdx.x & 15;
    int qt = blockIdx.x >> 4;
    int qb = qt * 16;
    int kvh = head >> 2;
    int lg = l >> 4, lr = l & 15;
    const float cls = 0.0883883476f * 1.44269504f;  // (1/sqrt(128)) * log2(e)

    s16x8 qf[4];
    const u16* qrow = Q + (size_t)(qb + lr) * 2048 + head * DH + lg * 8;
#pragma unroll
    for (int c = 0; c < 4; c++) qf[c] = *(const s16x8*)(qrow + c * 32);

    f32x4 oacc[8];
    f32x4 z4 = {0.f, 0.f, 0.f, 0.f};
#pragma unroll
    for (int f = 0; f < 8; f++) oacc[f] = z4;
    float m_run = -1e30f, l_run = 0.f;
    int qg = qb + lr;

    int nchunk = (qb + 16 + 31) >> 5;
    for (int ch = 0; ch < nchunk; ch++) {
        int kv0 = ch * 32;
        f32x4 st0 = z4, st1 = z4;
        const u16* krow0 = Kb + (size_t)(kv0 + lr) * 512 + kvh * DH + lg * 8;
        const u16* krow1 = krow0 + 16 * 512;
#pragma unroll
        for (int c = 0; c < 4; c++) {
            s16x8 kf = *(const s16x8*)(krow0 + c * 32);
            st0 = MFMA16(kf, qf[c], st0);
        }
#pragma unroll
        for (int c = 0; c < 4; c++) {
            s16x8 kf = *(const s16x8*)(krow1 + c * 32);
            st1 = MFMA16(kf, qf[c], st1);
        }
        // stage V transposed: Vt[d][kv], packed pairs along kv
        {
            int kvp = l >> 2, dq = (l & 3) * 32;
            const u16* v0 = Vb + (size_t)(kv0 + 2 * kvp) * 512 + kvh * DH + dq;
            const u16* v1 = v0 + 512;
#pragma unroll
            for (int j = 0; j < 32; j += 8) {
                s16x8 a = *(const s16x8*)(v0 + j);
                s16x8 b = *(const s16x8*)(v1 + j);
#pragma unroll
                for (int e = 0; e < 8; e++)
                    Vt[(dq + j + e) * 20 + kvp] = (u32)(u16)a[e] | ((u32)(u16)b[e] << 16);
            }
        }
        // softmax (stats per lane for q = qb + lr)
        float sv[8];
#pragma unroll
        for (int r = 0; r < 4; r++) {
            int kvg0 = kv0 + 4 * lg + r;
            sv[r] = (kvg0 <= qg) ? st0[r] * cls : -1e30f;
            sv[4 + r] = (kvg0 + 16 <= qg) ? st1[r] * cls : -1e30f;
        }
        float mx = sv[0];
#pragma unroll
        for (int i = 1; i < 8; i++) mx = fmaxf(mx, sv[i]);
        mx = fmaxf(mx, __shfl_xor(mx, 16));
        mx = fmaxf(mx, __shfl_xor(mx, 32));
        float m_new = fmaxf(m_run, mx);
        float fac = exp2f(m_run - m_new);
        float ssum = 0.f;
#pragma unroll
        for (int i = 0; i < 8; i++) { sv[i] = exp2f(sv[i] - m_new); ssum += sv[i]; }
        ssum += __shfl_xor(ssum, 16);
        ssum += __shfl_xor(ssum, 32);
        l_run = l_run * fac + ssum;
        m_run = m_new;
        // write P (bf16) to LDS: row = q-local (lr), col = kv-local
        *(u32*)&Plds[lr * 40 + 4 * lg]       = pack2(sv[0], sv[1]);
        *(u32*)&Plds[lr * 40 + 4 * lg + 2]   = pack2(sv[2], sv[3]);
        *(u32*)&Plds[lr * 40 + 16 + 4 * lg]     = pack2(sv[4], sv[5]);
        *(u32*)&Plds[lr * 40 + 16 + 4 * lg + 2] = pack2(sv[6], sv[7]);
        __syncthreads();
        // rescale O accumulator (O rows are q-local = 4*lg + r)
#pragma unroll
        for (int r = 0; r < 4; r++) {
            float fr = __shfl(fac, 4 * lg + r);
#pragma unroll
            for (int f = 0; f < 8; f++) oacc[f][r] *= fr;
        }
        // PV: A = P[16q x 32kv] from Plds, B = V[32kv x 16d] from Vt
        s16x8 pa = *(const s16x8*)&Plds[lr * 40 + lg * 8];
#pragma unroll
        for (int f = 0; f < 8; f++) {
            s16x8 vf = *(const s16x8*)&Vt[(16 * f + lr) * 20 + lg * 4];
            oacc[f] = MFMA16(pa, vf, oacc[f]);
        }
        __syncthreads();
    }

    float inv = 1.0f / l_run;
#pragma unroll
    for (int r = 0; r < 4; r++) {
        float ir = __shfl(inv, 4 * lg + r);
        size_t base = (size_t)(qb + 4 * lg + r) * 2048 + head * DH + lr;
#pragma unroll
        for (int f = 0; f < 8; f++)
            O[base + 16 * f] = f2bf(oacc[f][r] * ir);
    }
}

// ---------------------------------------------------------------------------
// silu(g) * u, in-place into G (both bf16, packed as u32 pairs)
// ---------------------------------------------------------------------------
__global__ __launch_bounds__(256) void silu_kernel(u32* __restrict__ G, const u32* __restrict__ U)
{
    size_t i = ((size_t)blockIdx.x * 256 + threadIdx.x) * 4;
    uint4 g = *(const uint4*)&G[i];
    uint4 u = *(const uint4*)&U[i];
    u32 go[4];
    u32 gi[4] = {g.x, g.y, g.z, g.w};
    u32 ui[4] = {u.x, u.y, u.z, u.w};
#pragma unroll
    for (int j = 0; j < 4; j++) {
        float g0 = bf2f((u16)(gi[j] & 0xffff)), g1 = bf2f((u16)(gi[j] >> 16));
        float u0 = bf2f((u16)(ui[j] & 0xffff)), u1 = bf2f((u16)(ui[j] >> 16));
        float s0 = g0 / (1.f + __expf(-g0));
        float s1 = g1 / (1.f + __expf(-g1));
        go[j] = pack2(s0 * u0, s1 * u1);
    }
    *(uint4*)&G[i] = make_uint4(go[0], go[1], go[2], go[3]);
}

// ---------------------------------------------------------------------------
extern "C" void kernel_launch(void* const* d_in, const int* in_sizes, int n_in,
                              void* d_out, int out_size, void* d_ws, size_t ws_size,
                              hipStream_t stream) {
    (void)in_sizes; (void)n_in; (void)out_size; (void)ws_size;
    const float* x     = (const float*)d_in[0];
    const float* cosb  = (const float*)d_in[1];
    const float* sinb  = (const float*)d_in[2];
    // d_in[3] text_idx, d_in[4] vae_idx: contiguous arange by construction
    const float* wq_t  = (const float*)d_in[5];
    const float* wk_t  = (const float*)d_in[6];
    const float* wv_t  = (const float*)d_in[7];
    const float* wo_t  = (const float*)d_in[8];
    const float* qn_t  = (const float*)d_in[9];
    const float* kn_t  = (const float*)d_in[10];
    const float* ln1_t = (const float*)d_in[11];
    const float* ln2_t = (const float*)d_in[12];
    const float* gate_t= (const float*)d_in[13];
    const float* up_t  = (const float*)d_in[14];
    const float* down_t= (const float*)d_in[15];
    const float* wq_v  = (const float*)d_in[16];
    const float* wk_v  = (const float*)d_in[17];
    const float* wv_v  = (const float*)d_in[18];
    const float* wo_v  = (const float*)d_in[19];
    const float* qn_v  = (const float*)d_in[20];
    const float* kn_v  = (const float*)d_in[21];
    const float* ln1_v = (const float*)d_in[22];
    const float* ln2_v = (const float*)d_in[23];
    const float* gate_v= (const float*)d_in[24];
    const float* up_v  = (const float*)d_in[25];
    const float* down_v= (const float*)d_in[26];
    float* out = (float*)d_out;

    char* ws = (char*)d_ws;
    size_t off = 0;
    auto carve = [&](size_t bytes) -> void* {
        void* p = ws + off;
        off += (bytes + 255) & ~(size_t)255;
        return p;
    };
    u16*  h    = (u16*)carve((size_t)L_TOK * HIDN * 2);
    float* qkv = (float*)carve((size_t)L_TOK * 3072 * 4);
    u16*  qb   = (u16*)carve((size_t)L_TOK * 2048 * 2);
    u16*  kb   = (u16*)carve((size_t)L_TOK * 512 * 2);
    u16*  vb   = (u16*)carve((size_t)L_TOK * 512 * 2);
    u16*  attn = (u16*)carve((size_t)L_TOK * 2048 * 2);
    float* x2  = (float*)carve((size_t)L_TOK * HIDN * 4);
    u16*  G    = (u16*)carve((size_t)L_TOK * DFFN * 2);
    u16*  U    = (u16*)carve((size_t)L_TOK * DFFN * 2);

    const int MT = NTXT;            // 256 text rows
    const int MV = L_TOK - NTXT;    // 2816 vae rows

    // 1. rms(x, ln1) -> h (bf16)
    rms_kernel<<<L_TOK, 256, 0, stream>>>(x, ln1_t, ln1_v, h);

    // 2. qkv projections -> qkv f32 (cols: q 0..2047, k 2048..2559, v 2560..3071)
    gemm_kernel<0><<<dim3(16, MT/128), 256, 0, stream>>>(h, HIDN, wq_t, 2048, qkv, 3072, nullptr, 0, HIDN);
    gemm_kernel<0><<<dim3( 4, MT/128), 256, 0, stream>>>(h, HIDN, wk_t,  512, qkv + 2048, 3072, nullptr, 0, HIDN);
    gemm_kernel<0><<<dim3( 4, MT/128), 256, 0, stream>>>(h, HIDN, wv_t,  512, qkv + 2560, 3072, nullptr, 0, HIDN);
    gemm_kernel<0><<<dim3(16, MV/128), 256, 0, stream>>>(h + (size_t)MT*HIDN, HIDN, wq_v, 2048, qkv + (size_t)MT*3072, 3072, nullptr, 0, HIDN);
    gemm_kernel<0><<<dim3( 4, MV/128), 256, 0, stream>>>(h + (size_t)MT*HIDN, HIDN, wk_v,  512, qkv + (size_t)MT*3072 + 2048, 3072, nullptr, 0, HIDN);
    gemm_kernel<0><<<dim3( 4, MV/128), 256, 0, stream>>>(h + (size_t)MT*HIDN, HIDN, wv_v,  512, qkv + (size_t)MT*3072 + 2560, 3072, nullptr, 0, HIDN);

    // 3. q/k rmsnorm + rope, v cast -> qb/kb/vb (bf16)
    qkv_post_kernel<<<dim3(24, L_TOK), 64, 0, stream>>>(qkv, cosb, sinb, qn_t, qn_v, kn_t, kn_v, qb, kb, vb);

    // 4. causal GQA flash attention -> attn (bf16, L x 2048)
    attn_kernel<<<dim3(L_TOK / 16 * 16), 64, 0, stream>>>(qb, kb, vb, attn);

    // 5. o-projection + residual -> x2 (f32)
    gemm_kernel<1><<<dim3(16, MT/128), 256, 0, stream>>>(attn, 2048, wo_t, 2048, x2, HIDN, x, HIDN, 2048);
    gemm_kernel<1><<<dim3(16, MV/128), 256, 0, stream>>>(attn + (size_t)MT*2048, 2048, wo_v, 2048, x2 + (size_t)MT*HIDN, HIDN, x + (size_t)MT*HIDN, HIDN, 2048);

    // 6. rms(x2, ln2) -> h (bf16, reuse)
    rms_kernel<<<L_TOK, 256, 0, stream>>>(x2, ln2_t, ln2_v, h);

    // 7. gate/up projections -> G, U (bf16)
    gemm_kernel<2><<<dim3(64, MT/128), 256, 0, stream>>>(h, HIDN, gate_t, DFFN, G, DFFN, nullptr, 0, HIDN);
    gemm_kernel<2><<<dim3(64, MT/128), 256, 0, stream>>>(h, HIDN, up_t,   DFFN, U, DFFN, nullptr, 0, HIDN);
    gemm_kernel<2><<<dim3(64, MV/128), 256, 0, stream>>>(h + (size_t)MT*HIDN, HIDN, gate_v, DFFN, G + (size_t)MT*DFFN, DFFN, nullptr, 0, HIDN);
    gemm_kernel<2><<<dim3(64, MV/128), 256, 0, stream>>>(h + (size_t)MT*HIDN, HIDN, up_v,   DFFN, U + (size_t)MT*DFFN, DFFN, nullptr, 0, HIDN);

    // 8. silu(G)*U -> G (bf16)
    silu_kernel<<<dim3((L_TOK * DFFN / 2) / (256 * 4)), 256, 0, stream>>>((u32*)G, (const u32*)U);

    // 9. down projection + residual(x2) -> out (f32)
    gemm_kernel<1><<<dim3(16, MT/128), 256, 0, stream>>>(G, DFFN, down_t, 2048, out, HIDN, x2, HIDN, DFFN);
    gemm_kernel<1><<<dim3(16, MV/128), 256, 0, stream>>>(G + (size_t)MT*DFFN, DFFN, down_v, 2048, out + (size_t)MT*HIDN, HIDN, x2 + (size_t)MT*HIDN, HIDN, DFFN);
}

// Round 4
// 1720.397 us; speedup vs baseline: 1.3697x; 1.3697x over previous
//
#include <hip/hip_runtime.h>
#include <hip/hip_bf16.h>

#define L_TOK 3072
#define HIDN  2048
#define NHQ   16
#define NHKV  4
#define DH    128
#define DFFN  8192
#define NTXT  256

typedef float f32x4 __attribute__((ext_vector_type(4)));
typedef short s16x8 __attribute__((ext_vector_type(8)));
typedef unsigned int u32;
typedef unsigned short u16;

__device__ __forceinline__ u16 f2bf(float f) {
    union { float f; u32 u; } v; v.f = f;
    u32 r = v.u + 0x7fffu + ((v.u >> 16) & 1u);
    return (u16)(r >> 16);
}
__device__ __forceinline__ float bf2f(u16 b) {
    union { u32 u; float f; } v; v.u = ((u32)b) << 16;
    return v.f;
}
__device__ __forceinline__ u32 pack2(float lo, float hi) {
    return (u32)f2bf(lo) | ((u32)f2bf(hi) << 16);
}

#define MFMA16(a, b, c) __builtin_amdgcn_mfma_f32_16x16x32_bf16((a), (b), (c), 0, 0, 0)

// async global->LDS, 16B per lane; lds base must be wave-uniform (HW adds lane*16B)
#define GLOAD16(g, l) \
    __builtin_amdgcn_global_load_lds((const __attribute__((address_space(1))) void*)(g), \
                                     (__attribute__((address_space(3))) void*)(l), 16, 0, 0)

// ---------------------------------------------------------------------------
// RMSNorm: f32 in -> bf16 out, weight selected by row<NTXT (text) else vae.
// ---------------------------------------------------------------------------
__global__ __launch_bounds__(256) void rms_kernel(
    const float* __restrict__ x, const float* __restrict__ w_t,
    const float* __restrict__ w_v, u16* __restrict__ out)
{
    int row = blockIdx.x;
    const float* w = (row < NTXT) ? w_t : w_v;
    const float* xr = x + (size_t)row * HIDN;
    int t = threadIdx.x;
    f32x4 a = *(const f32x4*)(xr + t * 8);
    f32x4 b = *(const f32x4*)(xr + t * 8 + 4);
    float s = 0.f;
#pragma unroll
    for (int i = 0; i < 4; i++) s += a[i] * a[i] + b[i] * b[i];
#pragma unroll
    for (int m = 32; m >= 1; m >>= 1) s += __shfl_xor(s, m);
    __shared__ float red[4];
    if ((t & 63) == 0) red[t >> 6] = s;
    __syncthreads();
    s = red[0] + red[1] + red[2] + red[3];
    float scale = rsqrtf(s * (1.0f / HIDN) + 1e-6f);
    f32x4 wa = *(const f32x4*)(w + t * 8);
    f32x4 wb = *(const f32x4*)(w + t * 8 + 4);
    u32 o[4];
    o[0] = pack2(a[0] * wa[0] * scale, a[1] * wa[1] * scale);
    o[1] = pack2(a[2] * wa[2] * scale, a[3] * wa[3] * scale);
    o[2] = pack2(b[0] * wb[0] * scale, b[1] * wb[1] * scale);
    o[3] = pack2(b[2] * wb[2] * scale, b[3] * wb[3] * scale);
    *(uint4*)(out + (size_t)row * HIDN + t * 8) = make_uint4(o[0], o[1], o[2], o[3]);
}

// ---------------------------------------------------------------------------
// Cast+transpose: W f32 [K][N] -> Wt bf16 [N][K]. 64x64 tiles, 256 threads.
// ---------------------------------------------------------------------------
__global__ __launch_bounds__(256) void castT_kernel(
    const float* __restrict__ W, u16* __restrict__ Wt, int N, int K)
{
    __shared__ __align__(16) u16 t[64][80];
    int t0 = threadIdx.x;
    int k0 = blockIdx.y * 64, n0 = blockIdx.x * 64;
    int kr = t0 >> 4;          // 0..15
    int nc = (t0 & 15) * 4;    // 0..60
#pragma unroll
    for (int i = 0; i < 4; i++) {
        int k = kr + i * 16;
        f32x4 v = *(const f32x4*)(W + (size_t)(k0 + k) * N + n0 + nc);
#pragma unroll
        for (int j = 0; j < 4; j++) t[nc + j][k] = f2bf(v[j]);
    }
    __syncthreads();
    int n = t0 >> 2;           // 0..63
    int kc = (t0 & 3) * 16;    // 0,16,32,48
    uint4 o0 = *(uint4*)&t[n][kc];
    uint4 o1 = *(uint4*)&t[n][kc + 8];
    u16* dst = Wt + (size_t)(n0 + n) * K + k0 + kc;
    *(uint4*)dst = o0;
    *(uint4*)(dst + 8) = o1;
}

// ---------------------------------------------------------------------------
// GEMM2: C[M,N] = A[M,K](bf16) * Bt[N,K](bf16)   (m97-style structure)
// 128x128 tile, BK=64, 4 waves, global_load_lds w=16, XOR-swizzled LDS.
// EPI: 0 = store f32, 1 = store f32 + residual, 2 = store bf16
// ---------------------------------------------------------------------------
template<int EPI>
__global__ __launch_bounds__(256) void gemm2_kernel(
    const u16* __restrict__ A, int lda,
    const u16* __restrict__ Bt, int ldb,
    void* __restrict__ Cv, int ldc,
    const float* __restrict__ R, int ldr,
    int K)
{
    __shared__ __align__(16) u16 As[128 * 64];
    __shared__ __align__(16) u16 Bs[128 * 64];

    int tid = threadIdx.x;
    int l = tid & 63, w = tid >> 6;
    int wr = w >> 1, wc = w & 1;
    int lg = l >> 4, lr = l & 15;
    int brow = blockIdx.y * 128, bcol = blockIdx.x * 128;

    f32x4 acc[4][4];
    f32x4 z4 = {0.f, 0.f, 0.f, 0.f};
#pragma unroll
    for (int m = 0; m < 4; m++)
#pragma unroll
        for (int n = 0; n < 4; n++) acc[m][n] = z4;

    // staging: wave w stages rows w*32..w*32+31 (4 instrs of 8 rows each).
    // LDS layout linear [row][64]; logical col-slot cs lands at physical
    // slot ps = cs ^ (row&7)  (achieved by inverse-swizzling the SOURCE).
    // lane i of an instr: row_off = i>>3, cs = (i&7) ^ (i>>3).
    int srow = w * 32 + (l >> 3);
    int scs  = (l & 7) ^ (l >> 3);
    const u16* aSrc = A + (size_t)(brow + srow) * lda + scs * 8;
    const u16* bSrc = Bt + (size_t)(bcol + srow) * ldb + scs * 8;

    for (int k0 = 0; k0 < K; k0 += 64) {
#pragma unroll
        for (int j = 0; j < 4; j++) {
            GLOAD16(aSrc + (size_t)j * 8 * lda + k0, &As[(w * 32 + j * 8) * 64]);
            GLOAD16(bSrc + (size_t)j * 8 * ldb + k0, &Bs[(w * 32 + j * 8) * 64]);
        }
        __syncthreads();   // drains vmcnt before barrier (compiler-inserted)

#pragma unroll
        for (int ks = 0; ks < 2; ks++) {
            s16x8 af[4], bf[4];
            int ps = ((ks * 4 + lg) ^ (lr & 7)) * 8;
#pragma unroll
            for (int m = 0; m < 4; m++)
                af[m] = *(const s16x8*)&As[(wr * 64 + m * 16 + lr) * 64 + ps];
#pragma unroll
            for (int n = 0; n < 4; n++)
                bf[n] = *(const s16x8*)&Bs[(wc * 64 + n * 16 + lr) * 64 + ps];
#pragma unroll
            for (int m = 0; m < 4; m++)
#pragma unroll
                for (int n = 0; n < 4; n++)
                    acc[m][n] = MFMA16(af[m], bf[n], acc[m][n]);
        }
        __syncthreads();
    }

#pragma unroll
    for (int m = 0; m < 4; m++) {
        int rowb = brow + wr * 64 + m * 16 + lg * 4;
#pragma unroll
        for (int n = 0; n < 4; n++) {
            int col = bcol + wc * 64 + n * 16 + lr;
#pragma unroll
            for (int r = 0; r < 4; r++) {
                float v = acc[m][n][r];
                size_t idx = (size_t)(rowb + r) * ldc + col;
                if (EPI == 0) {
                    ((float*)Cv)[idx] = v;
                } else if (EPI == 1) {
                    ((float*)Cv)[idx] = v + R[(size_t)(rowb + r) * ldr + col];
                } else {
                    ((u16*)Cv)[idx] = f2bf(v);
                }
            }
        }
    }
}

// ---------------------------------------------------------------------------
// Post-QKV: per (token, unit) with unit in [0,24): q-heads 0..15 (rms+rope),
// k-heads 16..19 (rms+rope), v-heads 20..23 (cast only). 64 threads.
// ---------------------------------------------------------------------------
__global__ __launch_bounds__(64) void qkv_post_kernel(
    const float* __restrict__ qkv,
    const float* __restrict__ cosb, const float* __restrict__ sinb,
    const float* __restrict__ qn_t, const float* __restrict__ qn_v,
    const float* __restrict__ kn_t, const float* __restrict__ kn_v,
    u16* __restrict__ qo, u16* __restrict__ ko, u16* __restrict__ vo)
{
    int tok = blockIdx.y;
    int unit = blockIdx.x;
    int lane = threadIdx.x;
    const float* base = qkv + (size_t)tok * 3072;

    if (unit < NHQ + NHKV) {
        int isq = (unit < NHQ);
        int h = isq ? unit : (unit - NHQ);
        const float* src = base + (isq ? h * DH : 2048 + h * DH);
        float x0 = src[lane], x1 = src[lane + 64];
        float ss = x0 * x0 + x1 * x1;
#pragma unroll
        for (int m = 32; m >= 1; m >>= 1) ss += __shfl_xor(ss, m);
        float sc = rsqrtf(ss * (1.0f / DH) + 1e-6f);
        const float* nw = isq ? (tok < NTXT ? qn_t : qn_v) : (tok < NTXT ? kn_t : kn_v);
        float n0 = x0 * nw[lane] * sc, n1 = x1 * nw[lane + 64] * sc;
        float c0 = cosb[(size_t)tok * DH + lane], c1 = cosb[(size_t)tok * DH + lane + 64];
        float s0 = sinb[(size_t)tok * DH + lane], s1 = sinb[(size_t)tok * DH + lane + 64];
        float r0 = n0 * c0 - n1 * s0;
        float r1 = n1 * c1 + n0 * s1;
        if (isq) {
            u16* dst = qo + (size_t)tok * 2048 + h * DH;
            dst[lane] = f2bf(r0); dst[lane + 64] = f2bf(r1);
        } else {
            u16* dst = ko + (size_t)tok * 512 + h * DH;
            dst[lane] = f2bf(r0); dst[lane + 64] = f2bf(r1);
        }
    } else {
        int h = unit - NHQ - NHKV;
        const float* src = base + 2560 + h * DH;
        u16* dst = vo + (size_t)tok * 512 + h * DH;
        dst[lane] = f2bf(src[lane]);
        dst[lane + 64] = f2bf(src[lane + 64]);
    }
}

// ---------------------------------------------------------------------------
// Flash attention, causal, GQA 16/4. 1 wave per block; block = (qtile of 16) x head.
// ---------------------------------------------------------------------------
__global__ __launch_bounds__(64) void attn_kernel(
    const u16* __restrict__ Q, const u16* __restrict__ Kb,
    const u16* __restrict__ Vb, u16* __restrict__ O)
{
    __shared__ __align__(16) u16 Plds[16 * 40];   // [q][kv] stride 40
    __shared__ __align__(16) u32 Vt[128 * 20];    // [d][kvpair] stride 20 u32

    int l = threadIdx.x;
    int head = blockIdx.x & 15;
    int qt = blockIdx.x >> 4;
    int qb = qt * 16;
    int kvh = head >> 2;
    int lg = l >> 4, lr = l & 15;
    const float cls = 0.0883883476f * 1.44269504f;  // (1/sqrt(128)) * log2(e)

    s16x8 qf[4];
    const u16* qrow = Q + (size_t)(qb + lr) * 2048 + head * DH + lg * 8;
#pragma unroll
    for (int c = 0; c < 4; c++) qf[c] = *(const s16x8*)(qrow + c * 32);

    f32x4 oacc[8];
    f32x4 z4 = {0.f, 0.f, 0.f, 0.f};
#pragma unroll
    for (int f = 0; f < 8; f++) oacc[f] = z4;
    float m_run = -1e30f, l_run = 0.f;
    int qg = qb + lr;

    int nchunk = (qb + 16 + 31) >> 5;
    for (int ch = 0; ch < nchunk; ch++) {
        int kv0 = ch * 32;
        f32x4 st0 = z4, st1 = z4;
        const u16* krow0 = Kb + (size_t)(kv0 + lr) * 512 + kvh * DH + lg * 8;
        const u16* krow1 = krow0 + 16 * 512;
#pragma unroll
        for (int c = 0; c < 4; c++) {
            s16x8 kf = *(const s16x8*)(krow0 + c * 32);
            st0 = MFMA16(kf, qf[c], st0);
        }
#pragma unroll
        for (int c = 0; c < 4; c++) {
            s16x8 kf = *(const s16x8*)(krow1 + c * 32);
            st1 = MFMA16(kf, qf[c], st1);
        }
        {
            int kvp = l >> 2, dq = (l & 3) * 32;
            const u16* v0 = Vb + (size_t)(kv0 + 2 * kvp) * 512 + kvh * DH + dq;
            const u16* v1 = v0 + 512;
#pragma unroll
            for (int j = 0; j < 32; j += 8) {
                s16x8 a = *(const s16x8*)(v0 + j);
                s16x8 b = *(const s16x8*)(v1 + j);
#pragma unroll
                for (int e = 0; e < 8; e++)
                    Vt[(dq + j + e) * 20 + kvp] = (u32)(u16)a[e] | ((u32)(u16)b[e] << 16);
            }
        }
        float sv[8];
#pragma unroll
        for (int r = 0; r < 4; r++) {
            int kvg0 = kv0 + 4 * lg + r;
            sv[r] = (kvg0 <= qg) ? st0[r] * cls : -1e30f;
            sv[4 + r] = (kvg0 + 16 <= qg) ? st1[r] * cls : -1e30f;
        }
        float mx = sv[0];
#pragma unroll
        for (int i = 1; i < 8; i++) mx = fmaxf(mx, sv[i]);
        mx = fmaxf(mx, __shfl_xor(mx, 16));
        mx = fmaxf(mx, __shfl_xor(mx, 32));
        float m_new = fmaxf(m_run, mx);
        float fac = exp2f(m_run - m_new);
        float ssum = 0.f;
#pragma unroll
        for (int i = 0; i < 8; i++) { sv[i] = exp2f(sv[i] - m_new); ssum += sv[i]; }
        ssum += __shfl_xor(ssum, 16);
        ssum += __shfl_xor(ssum, 32);
        l_run = l_run * fac + ssum;
        m_run = m_new;
        *(u32*)&Plds[lr * 40 + 4 * lg]       = pack2(sv[0], sv[1]);
        *(u32*)&Plds[lr * 40 + 4 * lg + 2]   = pack2(sv[2], sv[3]);
        *(u32*)&Plds[lr * 40 + 16 + 4 * lg]     = pack2(sv[4], sv[5]);
        *(u32*)&Plds[lr * 40 + 16 + 4 * lg + 2] = pack2(sv[6], sv[7]);
        __syncthreads();
#pragma unroll
        for (int r = 0; r < 4; r++) {
            float fr = __shfl(fac, 4 * lg + r);
#pragma unroll
            for (int f = 0; f < 8; f++) oacc[f][r] *= fr;
        }
        s16x8 pa = *(const s16x8*)&Plds[lr * 40 + lg * 8];
#pragma unroll
        for (int f = 0; f < 8; f++) {
            s16x8 vf = *(const s16x8*)&Vt[(16 * f + lr) * 20 + lg * 4];
            oacc[f] = MFMA16(pa, vf, oacc[f]);
        }
        __syncthreads();
    }

    float inv = 1.0f / l_run;
#pragma unroll
    for (int r = 0; r < 4; r++) {
        float ir = __shfl(inv, 4 * lg + r);
        size_t base = (size_t)(qb + 4 * lg + r) * 2048 + head * DH + lr;
#pragma unroll
        for (int f = 0; f < 8; f++)
            O[base + 16 * f] = f2bf(oacc[f][r] * ir);
    }
}

// ---------------------------------------------------------------------------
// silu(g) * u, in-place into G (both bf16, packed as u32 pairs)
// ---------------------------------------------------------------------------
__global__ __launch_bounds__(256) void silu_kernel(u32* __restrict__ G, const u32* __restrict__ U)
{
    size_t i = ((size_t)blockIdx.x * 256 + threadIdx.x) * 4;
    uint4 g = *(const uint4*)&G[i];
    uint4 u = *(const uint4*)&U[i];
    u32 go[4];
    u32 gi[4] = {g.x, g.y, g.z, g.w};
    u32 ui[4] = {u.x, u.y, u.z, u.w};
#pragma unroll
    for (int j = 0; j < 4; j++) {
        float g0 = bf2f((u16)(gi[j] & 0xffff)), g1 = bf2f((u16)(gi[j] >> 16));
        float u0 = bf2f((u16)(ui[j] & 0xffff)), u1 = bf2f((u16)(ui[j] >> 16));
        float s0 = g0 / (1.f + __expf(-g0));
        float s1 = g1 / (1.f + __expf(-g1));
        go[j] = pack2(s0 * u0, s1 * u1);
    }
    *(uint4*)&G[i] = make_uint4(go[0], go[1], go[2], go[3]);
}

// ---------------------------------------------------------------------------
extern "C" void kernel_launch(void* const* d_in, const int* in_sizes, int n_in,
                              void* d_out, int out_size, void* d_ws, size_t ws_size,
                              hipStream_t stream) {
    (void)in_sizes; (void)n_in; (void)out_size; (void)ws_size;
    const float* x     = (const float*)d_in[0];
    const float* cosb  = (const float*)d_in[1];
    const float* sinb  = (const float*)d_in[2];
    const float* wq_t  = (const float*)d_in[5];
    const float* wk_t  = (const float*)d_in[6];
    const float* wv_t  = (const float*)d_in[7];
    const float* wo_t  = (const float*)d_in[8];
    const float* qn_t  = (const float*)d_in[9];
    const float* kn_t  = (const float*)d_in[10];
    const float* ln1_t = (const float*)d_in[11];
    const float* ln2_t = (const float*)d_in[12];
    const float* gate_t= (const float*)d_in[13];
    const float* up_t  = (const float*)d_in[14];
    const float* down_t= (const float*)d_in[15];
    const float* wq_v  = (const float*)d_in[16];
    const float* wk_v  = (const float*)d_in[17];
    const float* wv_v  = (const float*)d_in[18];
    const float* wo_v  = (const float*)d_in[19];
    const float* qn_v  = (const float*)d_in[20];
    const float* kn_v  = (const float*)d_in[21];
    const float* ln1_v = (const float*)d_in[22];
    const float* ln2_v = (const float*)d_in[23];
    const float* gate_v= (const float*)d_in[24];
    const float* up_v  = (const float*)d_in[25];
    const float* down_v= (const float*)d_in[26];
    float* out = (float*)d_out;

    char* ws = (char*)d_ws;
    size_t off = 0;
    auto carve = [&](size_t bytes) -> void* {
        void* p = ws + off;
        off += (bytes + 255) & ~(size_t)255;
        return p;
    };
    u16*  h    = (u16*)carve((size_t)L_TOK * HIDN * 2);
    float* qkv = (float*)carve((size_t)L_TOK * 3072 * 4);
    u16*  qb   = (u16*)carve((size_t)L_TOK * 2048 * 2);
    u16*  kb   = (u16*)carve((size_t)L_TOK * 512 * 2);
    u16*  vb   = (u16*)carve((size_t)L_TOK * 512 * 2);
    u16*  attn = (u16*)carve((size_t)L_TOK * 2048 * 2);
    float* x2  = (float*)carve((size_t)L_TOK * HIDN * 4);
    u16*  G    = (u16*)carve((size_t)L_TOK * DFFN * 2);
    u16*  U    = (u16*)carve((size_t)L_TOK * DFFN * 2);
    u16*  wbuf = (u16*)carve((size_t)DFFN * HIDN * 2);  // rotating bf16 weight (max 33.6MB)

    const int MT = NTXT;            // 256 text rows
    const int MV = L_TOK - NTXT;    // 2816 vae rows

    // cast W[K][N] -> wbuf[N][K] then GEMM  C[M,N] = A * wbuf^T
    auto cg = [&](int EPI, const u16* A, int lda, const float* W, int N, int K,
                  void* C, int ldc, const float* R, int ldr, int M) {
        castT_kernel<<<dim3(N / 64, K / 64), 256, 0, stream>>>(W, wbuf, N, K);
        dim3 g(N / 128, M / 128);
        if (EPI == 0)      gemm2_kernel<0><<<g, 256, 0, stream>>>(A, lda, wbuf, K, C, ldc, R, ldr, K);
        else if (EPI == 1) gemm2_kernel<1><<<g, 256, 0, stream>>>(A, lda, wbuf, K, C, ldc, R, ldr, K);
        else               gemm2_kernel<2><<<g, 256, 0, stream>>>(A, lda, wbuf, K, C, ldc, R, ldr, K);
    };

    // 1. rms(x, ln1) -> h (bf16)
    rms_kernel<<<L_TOK, 256, 0, stream>>>(x, ln1_t, ln1_v, h);

    // 2. qkv projections -> qkv f32 (cols: q 0..2047, k 2048..2559, v 2560..3071)
    cg(0, h, HIDN, wq_t, 2048, HIDN, qkv, 3072, nullptr, 0, MT);
    cg(0, h, HIDN, wk_t,  512, HIDN, qkv + 2048, 3072, nullptr, 0, MT);
    cg(0, h, HIDN, wv_t,  512, HIDN, qkv + 2560, 3072, nullptr, 0, MT);
    cg(0, h + (size_t)MT * HIDN, HIDN, wq_v, 2048, HIDN, qkv + (size_t)MT * 3072, 3072, nullptr, 0, MV);
    cg(0, h + (size_t)MT * HIDN, HIDN, wk_v,  512, HIDN, qkv + (size_t)MT * 3072 + 2048, 3072, nullptr, 0, MV);
    cg(0, h + (size_t)MT * HIDN, HIDN, wv_v,  512, HIDN, qkv + (size_t)MT * 3072 + 2560, 3072, nullptr, 0, MV);

    // 3. q/k rmsnorm + rope, v cast -> qb/kb/vb (bf16)
    qkv_post_kernel<<<dim3(24, L_TOK), 64, 0, stream>>>(qkv, cosb, sinb, qn_t, qn_v, kn_t, kn_v, qb, kb, vb);

    // 4. causal GQA flash attention -> attn (bf16, L x 2048)
    attn_kernel<<<dim3(L_TOK / 16 * 16), 64, 0, stream>>>(qb, kb, vb, attn);

    // 5. o-projection + residual -> x2 (f32)
    cg(1, attn, 2048, wo_t, 2048, 2048, x2, HIDN, x, HIDN, MT);
    cg(1, attn + (size_t)MT * 2048, 2048, wo_v, 2048, 2048, x2 + (size_t)MT * HIDN, HIDN, x + (size_t)MT * HIDN, HIDN, MV);

    // 6. rms(x2, ln2) -> h (bf16, reuse)
    rms_kernel<<<L_TOK, 256, 0, stream>>>(x2, ln2_t, ln2_v, h);

    // 7. gate/up projections -> G, U (bf16)
    cg(2, h, HIDN, gate_t, DFFN, HIDN, G, DFFN, nullptr, 0, MT);
    cg(2, h, HIDN, up_t,   DFFN, HIDN, U, DFFN, nullptr, 0, MT);
    cg(2, h + (size_t)MT * HIDN, HIDN, gate_v, DFFN, HIDN, G + (size_t)MT * DFFN, DFFN, nullptr, 0, MV);
    cg(2, h + (size_t)MT * HIDN, HIDN, up_v,   DFFN, HIDN, U + (size_t)MT * DFFN, DFFN, nullptr, 0, MV);

    // 8. silu(G)*U -> G (bf16)
    silu_kernel<<<dim3((L_TOK * DFFN / 2) / (256 * 4)), 256, 0, stream>>>((u32*)G, (const u32*)U);

    // 9. down projection + residual(x2) -> out (f32)
    cg(1, G, DFFN, down_t, 2048, DFFN, out, HIDN, x2, HIDN, MT);
    cg(1, G + (size_t)MT * DFFN, DFFN, down_v, 2048, DFFN, out + (size_t)MT * HIDN, HIDN, x2 + (size_t)MT * HIDN, HIDN, MV);
}